// Round 2
// baseline (301.968 us; speedup 1.0000x reference)
//
#include <hip/hip_runtime.h>

// StealNMSLoss fused kernel for MI355X (gfx950).  Round 2.
//
// Math notes (verified bit-exact vs reference in round 1):
//  - Composed Sobel-of-Sobel on a one-hot mask gives exact integer stencils /64:
//      gxx = [1,4,6,4,1]_h (x) [1,0,-2,0,1]_w / 64
//      gxy = [-1,-2,0,2,1]_h (x) [-1,-2,0,2,1]_w / 64
//      gyy = [1,0,-2,0,1]_h (x) [1,4,6,4,1]_w / 64
//  - dir = f(round(atan(a)*5/pi)) collapses to threshold tests on |a| vs
//    tan(pi/10), tan(3pi/10); inputs quantized to n/64 keep boundaries far
//    from fp32 rounding distance.
//  - Only interior [2,H-2) x [2,W-2) contributes; dirs 1 and 3 share the
//    anti-diagonal denominator.
//
// Round 2 structural change: one (batch,class,tile) per block -> 8192 blocks,
// ONE barrier per block (was 16), ~6 resident blocks/CU for latency hiding.
// Round 1 was latency-bound: VALUBusy 40%, HBM 7.7%, occupancy 22%.

#define Bn 4
#define Cn 16
#define Hn 512
#define Wn 1024
#define TW 128           // output cols per block
#define TH 32            // output rows per block
#define LW 132           // TW + 4 halo
#define LH 36            // TH + 4 halo
#define NT 256           // 4 waves

#define EPSF 1.1920928955078125e-07f   // float32 eps
#define T1C 0.32491969623290623f       // tan(pi/10)
#define T2C 1.3763819204711735f        // tan(3pi/10)

typedef unsigned long long u64;
typedef unsigned int u32;

static __device__ __forceinline__ float fast_rcp(float x) {
#if __has_builtin(__builtin_amdgcn_rcpf)
  return __builtin_amdgcn_rcpf(x);   // v_rcp_f32, ~1 ulp: fine at 2% tolerance
#else
  return 1.0f / x;
#endif
}

__global__ __launch_bounds__(NT)
void steal_nms_kernel(const float* __restrict__ pred,
                      const int* __restrict__ labels,
                      float* __restrict__ out)
{
  __shared__ unsigned char labt[LH][LW];  // label tile (bytes)
  __shared__ float ext[LH][LW];           // exp(pred) tile
  __shared__ float wsum[NT/64];

  const int w0 = blockIdx.x * TW;
  const int h0 = blockIdx.y * TH;
  const int bz = blockIdx.z;
  const int b  = bz >> 4;        // batch
  const int c  = bz & 15;        // class
  const int tid = threadIdx.x;

  // ---- stage label tile (u32-packed; clamped coords only feed
  //      never-summed border outputs) ----
  for (int i = tid; i < LH * (LW/4); i += NT) {
    int row  = i / (LW/4);
    int col4 = (i - row*(LW/4)) * 4;
    int gh = h0 - 2 + row; gh = min(max(gh, 0), Hn-1);
    const int* lrow = labels + gh * Wn;
    u32 v = 0;
    #pragma unroll
    for (int k = 0; k < 4; ++k) {
      int gw = w0 - 2 + col4 + k; gw = min(max(gw, 0), Wn-1);
      v |= (u32)(lrow[gw] & 0xff) << (8*k);
    }
    *(u32*)&labt[row][col4] = v;
  }

  // ---- stage exp tile for this block's class (float2-coalesced) ----
  {
    const float* plane = pred + (size_t)(b*Cn + c) * (size_t)(Hn*Wn);
    for (int i = tid; i < LH*(LW/2); i += NT) {
      int row = i / (LW/2);
      int col = (i - row*(LW/2)) * 2;
      int gh = h0 - 2 + row; gh = min(max(gh, 0), Hn-1);
      int ga = w0 - 2 + col;
      int gb = ga + 1;
      ga = min(max(ga, 0), Wn-1);
      gb = min(max(gb, 0), Wn-1);
      const float* prow = plane + gh*Wn;
      float e0 = __expf(prow[ga]);
      float e1 = __expf(prow[gb]);
      *(float2*)&ext[row][col] = make_float2(e0, e1);
    }
  }
  __syncthreads();   // the ONLY barrier before the reduction

  const int lane = tid & 63;
  const int wq   = tid >> 6;     // wave id: rows [8*wq, 8*wq+8)
  const int hr0  = wq * 8;

  // ---- per-lane 6-byte label windows -> 0/1 mask bytes (SWAR zero-detect;
  //      window bytes <=15, so (0x80 - x) & 0x80 flags x==0 exactly) ----
  u64 mm[12];
  {
    const int byte0 = 2*lane;
    const int j0 = byte0 >> 2;
    const int sh = (byte0 & 3) * 8;
    const u64 crep = 0x0101010101010101ULL * (u32)c;
    const u64 m80  = 0x8080808080808080ULL;
    #pragma unroll
    for (int r = 0; r < 12; ++r) {
      const u32* rowp = (const u32*)&labt[hr0 + r][0];
      u64 lo = rowp[j0];
      u64 hi = rowp[j0 + 1];
      u64 wvr = ((hi << 32) | lo) >> sh;   // bytes 0..5 = window cols -2..+3
      u64 x = wvr ^ crep;
      mm[r] = ((m80 - x) & m80) >> 7;
    }
  }

  const int gw0 = w0 + 2*lane;
  const bool wvalid0 = (gw0     >= 2) && (gw0     < Wn-2);
  const bool wvalid1 = (gw0 + 1 >= 2) && (gw0 + 1 < Wn-2);

  float acc = 0.f;

  // ---- rolling 4-row exp register window, prefill 3 rows ----
  float exr[4][5];
  const int fb = 2*lane;
  #pragma unroll
  for (int r = 0; r < 3; ++r) {
    float2 p0 = *(const float2*)&ext[hr0 + r][fb];
    float2 p1 = *(const float2*)&ext[hr0 + r][fb + 2];
    exr[r][0] = p0.x; exr[r][1] = p0.y;
    exr[r][2] = p1.x; exr[r][3] = p1.y;
    exr[r][4] = ext[hr0 + r][fb + 4];
  }

  #pragma unroll
  for (int i = 0; i < 8; ++i) {
    { // load newest row (array row hr0+i+3) into rotating slot
      const int rn = (i + 3) & 3;
      float2 p0 = *(const float2*)&ext[hr0 + i + 3][fb];
      float2 p1 = *(const float2*)&ext[hr0 + i + 3][fb + 2];
      exr[rn][0] = p0.x; exr[rn][1] = p0.y;
      exr[rn][2] = p1.x; exr[rn][3] = p1.y;
      exr[rn][4] = ext[hr0 + i + 3][fb + 4];
    }

    // ---- packed-byte vertical sums (per window col, all 6 cols at once) ----
    // A  = rows . [1,4,6,4,1]            in [0,16]
    // Bb = rows . [-1,-2,0,2,1] + 4      in [1,7]
    // Cb = rows . [1,0,-2,0,1]  + 4      in [2,6]
    u64 m0 = mm[i], m1 = mm[i+1], m2 = mm[i+2], m3 = mm[i+3], m4 = mm[i+4];
    u64 s13 = m1 + m3;
    u64 A  = m0 + m4 + (s13 << 2) + (m2 << 2) + (m2 << 1);
    u64 Bb = 0x0404040404040404ULL + (m3 << 1) + m4 - m0 - (m1 << 1);
    u64 Cb = 0x0404040404040404ULL + m0 + m4 - (m2 << 1);

    #define BY(x,k) ((int)((u32)((x) >> (8*(k))) & 0xffu))
    int A0=BY(A,0), A1=BY(A,1), A2=BY(A,2), A3=BY(A,3), A4=BY(A,4), A5=BY(A,5);
    int B0=BY(Bb,0), B1=BY(Bb,1), B2=BY(Bb,2), B3=BY(Bb,3), B4=BY(Bb,4), B5=BY(Bb,5);
    int C0=BY(Cb,0), C1=BY(Cb,1), C2=BY(Cb,2), C3=BY(Cb,3), C4=BY(Cb,4), C5=BY(Cb,5);
    #undef BY

    // horizontal dots (64*g values, exact ints; biases cancel where sum==0)
    int gxx0 = A0 + A4 - 2*A2;
    int gxx1 = A1 + A5 - 2*A3;
    int gxyS0 = 2*(B3 - B1) + (B4 - B0);       // sign(gxy) only
    int gxyS1 = 2*(B4 - B2) + (B5 - B1);
    int gyy0 = C0 + C4 + 4*(C1 + C3) + 6*C2 - 64;
    int gyy1 = C1 + C5 + 4*(C2 + C4) + 6*C3 - 64;

    // ---- atan-free direction classification ----
    float den0 = fmaf((float)gxx0, 0.015625f, EPSF);   // gxx/64 + eps, exact
    float den1 = fmaf((float)gxx1, 0.015625f, EPSF);
    float gy0 = (float)gyy0 * 0.015625f;
    float gy1 = (float)gyy1 * 0.015625f;
    float num0 = (gxyS0 > 0) ? -gy0 : gy0;             // s = sign(-gxy+eps)
    float num1 = (gxyS1 > 0) ? -gy1 : gy1;
    float an0 = fabsf(gy0), an1 = fabsf(gy1);
    float ad0 = fabsf(den0), ad1 = fabsf(den1);
    int rb0 = (int)(an0 >= T1C*ad0) + (int)(an0 >= T2C*ad0);
    int rb1 = (int)(an1 >= T1C*ad1) + (int)(an1 >= T2C*ad1);
    bool ng0 = ((__float_as_int(num0) ^ __float_as_int(den0)) < 0);
    bool ng1 = ((__float_as_int(num1) ^ __float_as_int(den1)) < 0);
    // r=+1->1, +2->2, 0->0, -1->0, -2->3
    int dir0 = ng0 ? ((rb0 == 2) ? 3 : 0) : rb0;
    int dir1 = ng1 ? ((rb1 == 2) ? 3 : 0) : rb1;

    // window rows: r0 = gh-2 .. r3 = gh+1 ; cols: [k .. k+4] = gw-2 .. gw+2
    const float* r0 = exr[(i+0)&3];
    const float* r1 = exr[(i+1)&3];
    const float* r2 = exr[(i+2)&3];
    const float* r3 = exr[(i+3)&3];

    float t12 = r2[1] + r2[2];
    float D0a = t12 + r2[0] + r2[3];                    // horizontal
    float D0b = t12 + r2[3] + r2[4];
    float D2a = (r0[2] + r1[2]) + (r2[2] + r3[2]);      // vertical
    float D2b = (r0[3] + r1[3]) + (r2[3] + r3[3]);
    float Dda = (r0[3] + r1[2]) + (r2[1] + r3[0]);      // anti-diagonal (dir 1&3)
    float Ddb = (r0[4] + r1[3]) + (r2[2] + r3[1]);

    float dena = (dir0 == 0) ? D0a : ((dir0 == 2) ? D2a : Dda);
    float denb = (dir1 == 0) ? D0b : ((dir1 == 2) ? D2b : Ddb);

    const int gh = h0 + hr0 + i;
    const bool hv = (gh >= 2) && (gh < Hn-2);
    float na = (hv && wvalid0) ? r2[2] : 0.f;
    float nb = (hv && wvalid1) ? r2[3] : 0.f;
    acc += na * fast_rcp(dena);
    acc += nb * fast_rcp(denb);
  }

  // ---- reduce: wave shuffle -> LDS -> one atomic per block ----
  #pragma unroll
  for (int off = 32; off > 0; off >>= 1)
    acc += __shfl_down(acc, off);
  if (lane == 0) wsum[wq] = acc;
  __syncthreads();
  if (tid == 0) {
    float s = 0.f;
    #pragma unroll
    for (int q = 0; q < NT/64; ++q) s += wsum[q];
    atomicAdd(out, s);
  }
}

extern "C" void kernel_launch(void* const* d_in, const int* in_sizes, int n_in,
                              void* d_out, int out_size, void* d_ws, size_t ws_size,
                              hipStream_t stream) {
  (void)in_sizes; (void)n_in; (void)d_ws; (void)ws_size; (void)out_size;
  const float* pred   = (const float*)d_in[0];
  const int*   labels = (const int*)d_in[1];
  float* out = (float*)d_out;

  // d_out is re-poisoned before every timed launch
  hipMemsetAsync(out, 0, sizeof(float), stream);

  dim3 grid(Wn/TW, Hn/TH, Bn*Cn);   // 8 x 16 x 64 = 8192 blocks, 1 class each
  steal_nms_kernel<<<grid, NT, 0, stream>>>(pred, labels, out);
}

// Round 3
// 265.434 us; speedup vs baseline: 1.1376x; 1.1376x over previous
//
#include <hip/hip_runtime.h>

// StealNMSLoss fused kernel for MI355X (gfx950).  Round 3.
//
// Math notes (verified bit-exact vs reference in rounds 1-2):
//  - Composed Sobel-of-Sobel on a one-hot mask gives exact integer stencils /64:
//      gxx = [1,4,6,4,1]_h (x) [1,0,-2,0,1]_w / 64
//      gxy = [-1,-2,0,2,1]_h (x) [-1,-2,0,2,1]_w / 64
//      gyy = [1,0,-2,0,1]_h (x) [1,4,6,4,1]_w / 64
//  - dir = f(round(atan(a)*5/pi)) collapses to threshold tests on |a| vs
//    tan(pi/10), tan(3pi/10); inputs quantized to n/64 keep boundaries far
//    from fp32 rounding distance.
//  - Only interior [2,H-2) x [2,W-2) contributes; dirs 1 and 3 share the
//    anti-diagonal denominator.
//
// Round 3: TH 32->16 (LDS 24->13.2 KB: 8 blocks/CU, wave-slot limited, not
// LDS-limited), interior fast-path staging (float4/int4, no clamps, 70% of
// blocks), atomics spread over 256 ws slots + tiny reduce kernel.
// Rounds 1/2 post-mortem: latency-bound (VALU 45%, HBM 7.7%, occ 31%).

#define Bn 4
#define Cn 16
#define Hn 512
#define Wn 1024
#define TW 128           // output cols per block
#define TH 16            // output rows per block
#define LW 132           // TW + 4 halo
#define LH 20            // TH + 4 halo
#define NT 256           // 4 waves

#define EPSF 1.1920928955078125e-07f   // float32 eps
#define T1C 0.32491969623290623f       // tan(pi/10)
#define T2C 1.3763819204711735f        // tan(3pi/10)

typedef unsigned long long u64;
typedef unsigned int u32;
typedef float f4u __attribute__((ext_vector_type(4), aligned(4)));  // 4B-aligned float4
typedef int   i4u __attribute__((ext_vector_type(4), aligned(4)));  // 4B-aligned int4

static __device__ __forceinline__ float fast_rcp(float x) {
#if __has_builtin(__builtin_amdgcn_rcpf)
  return __builtin_amdgcn_rcpf(x);   // v_rcp_f32, ~1 ulp: fine at 2% tolerance
#else
  return 1.0f / x;
#endif
}

__global__ __launch_bounds__(NT)
void steal_nms_kernel(const float* __restrict__ pred,
                      const int* __restrict__ labels,
                      float* __restrict__ ws)
{
  __shared__ unsigned char labt[LH][LW];  // label tile (bytes)
  __shared__ float ext[LH][LW];           // exp(pred) tile
  __shared__ float wsum[NT/64];

  const int w0 = blockIdx.x * TW;
  const int h0 = blockIdx.y * TH;
  const int bz = blockIdx.z;
  const int b  = bz >> 4;        // batch
  const int c  = bz & 15;        // class
  const int tid = threadIdx.x;

  const float* plane = pred + (size_t)(b*Cn + c) * (size_t)(Hn*Wn);
  // interior: the whole staged window [h0-2,h0+TH+2) x [w0-2,w0+TW+2) is in-range
  const bool interior = (h0 >= 2) && (h0 + TH + 2 <= Hn) &&
                        (w0 >= 2) && (w0 + TW + 2 <= Wn);

  if (interior) {
    // ---- fast path: clamp-free vector staging (70% of blocks) ----
    const int*   lb = labels + (size_t)(h0-2)*Wn + (w0-2);
    const float* pb = plane  + (size_t)(h0-2)*Wn + (w0-2);
    for (int i = tid; i < LH*33; i += NT) {      // 33 quads per 132-col row
      int row = i / 33;
      int c4  = (i - row*33) * 4;
      i4u L = *(const i4u*)(lb + row*Wn + c4);
      u32 v = (u32)L.x | ((u32)L.y << 8) | ((u32)L.z << 16) | ((u32)L.w << 24);
      *(u32*)&labt[row][c4] = v;
      f4u p = *(const f4u*)(pb + row*Wn + c4);
      float4 e;
      e.x = __expf(p.x); e.y = __expf(p.y); e.z = __expf(p.z); e.w = __expf(p.w);
      *(float4*)&ext[row][c4] = e;
    }
  } else {
    // ---- edge path: per-element clamped staging (round-2 code) ----
    for (int i = tid; i < LH * (LW/4); i += NT) {
      int row  = i / (LW/4);
      int col4 = (i - row*(LW/4)) * 4;
      int gh = h0 - 2 + row; gh = min(max(gh, 0), Hn-1);
      const int* lrow = labels + gh * Wn;
      u32 v = 0;
      #pragma unroll
      for (int k = 0; k < 4; ++k) {
        int gw = w0 - 2 + col4 + k; gw = min(max(gw, 0), Wn-1);
        v |= (u32)(lrow[gw] & 0xff) << (8*k);
      }
      *(u32*)&labt[row][col4] = v;
    }
    for (int i = tid; i < LH*(LW/2); i += NT) {
      int row = i / (LW/2);
      int col = (i - row*(LW/2)) * 2;
      int gh = h0 - 2 + row; gh = min(max(gh, 0), Hn-1);
      int ga = w0 - 2 + col;
      int gb = ga + 1;
      ga = min(max(ga, 0), Wn-1);
      gb = min(max(gb, 0), Wn-1);
      const float* prow = plane + gh*Wn;
      float e0 = __expf(prow[ga]);
      float e1 = __expf(prow[gb]);
      *(float2*)&ext[row][col] = make_float2(e0, e1);
    }
  }
  __syncthreads();   // the ONLY barrier before the reduction

  const int lane = tid & 63;
  const int wq   = tid >> 6;     // wave id: rows [4*wq, 4*wq+4)
  const int hr0  = wq * 4;

  // ---- per-lane 6-byte label windows -> 0/1 mask bytes (SWAR zero-detect;
  //      window bytes <=15, so (0x80 - x) & 0x80 flags x==0 exactly) ----
  u64 mm[TH/4 + 4];
  {
    const int byte0 = 2*lane;
    const int j0 = byte0 >> 2;
    const int sh = (byte0 & 3) * 8;
    const u64 crep = 0x0101010101010101ULL * (u32)c;
    const u64 m80  = 0x8080808080808080ULL;
    #pragma unroll
    for (int r = 0; r < TH/4 + 4; ++r) {
      const u32* rowp = (const u32*)&labt[hr0 + r][0];
      u64 lo = rowp[j0];
      u64 hi = rowp[j0 + 1];
      u64 wvr = ((hi << 32) | lo) >> sh;   // bytes 0..5 = window cols -2..+3
      u64 x = wvr ^ crep;
      mm[r] = ((m80 - x) & m80) >> 7;
    }
  }

  const int gw0 = w0 + 2*lane;
  const bool wvalid0 = (gw0     >= 2) && (gw0     < Wn-2);
  const bool wvalid1 = (gw0 + 1 >= 2) && (gw0 + 1 < Wn-2);

  float acc = 0.f;

  // ---- rolling 4-row exp register window, prefill 3 rows ----
  float exr[4][5];
  const int fb = 2*lane;
  #pragma unroll
  for (int r = 0; r < 3; ++r) {
    float2 p0 = *(const float2*)&ext[hr0 + r][fb];
    float2 p1 = *(const float2*)&ext[hr0 + r][fb + 2];
    exr[r][0] = p0.x; exr[r][1] = p0.y;
    exr[r][2] = p1.x; exr[r][3] = p1.y;
    exr[r][4] = ext[hr0 + r][fb + 4];
  }

  #pragma unroll
  for (int i = 0; i < TH/4; ++i) {
    { // load newest row (array row hr0+i+3) into rotating slot
      const int rn = (i + 3) & 3;
      float2 p0 = *(const float2*)&ext[hr0 + i + 3][fb];
      float2 p1 = *(const float2*)&ext[hr0 + i + 3][fb + 2];
      exr[rn][0] = p0.x; exr[rn][1] = p0.y;
      exr[rn][2] = p1.x; exr[rn][3] = p1.y;
      exr[rn][4] = ext[hr0 + i + 3][fb + 4];
    }

    // ---- packed-byte vertical sums (per window col, all 6 cols at once) ----
    // A  = rows . [1,4,6,4,1]            in [0,16]
    // Bb = rows . [-1,-2,0,2,1] + 4      in [1,7]
    // Cb = rows . [1,0,-2,0,1]  + 4      in [2,6]
    u64 m0 = mm[i], m1 = mm[i+1], m2 = mm[i+2], m3 = mm[i+3], m4 = mm[i+4];
    u64 s13 = m1 + m3;
    u64 A  = m0 + m4 + (s13 << 2) + (m2 << 2) + (m2 << 1);
    u64 Bb = 0x0404040404040404ULL + (m3 << 1) + m4 - m0 - (m1 << 1);
    u64 Cb = 0x0404040404040404ULL + m0 + m4 - (m2 << 1);

    #define BY(x,k) ((int)((u32)((x) >> (8*(k))) & 0xffu))
    int A0=BY(A,0), A1=BY(A,1), A2=BY(A,2), A3=BY(A,3), A4=BY(A,4), A5=BY(A,5);
    int B0=BY(Bb,0), B1=BY(Bb,1), B2=BY(Bb,2), B3=BY(Bb,3), B4=BY(Bb,4), B5=BY(Bb,5);
    int C0=BY(Cb,0), C1=BY(Cb,1), C2=BY(Cb,2), C3=BY(Cb,3), C4=BY(Cb,4), C5=BY(Cb,5);
    #undef BY

    // horizontal dots (64*g values, exact ints; biases cancel where sum==0)
    int gxx0 = A0 + A4 - 2*A2;
    int gxx1 = A1 + A5 - 2*A3;
    int gxyS0 = 2*(B3 - B1) + (B4 - B0);       // sign(gxy) only
    int gxyS1 = 2*(B4 - B2) + (B5 - B1);
    int gyy0 = C0 + C4 + 4*(C1 + C3) + 6*C2 - 64;
    int gyy1 = C1 + C5 + 4*(C2 + C4) + 6*C3 - 64;

    // ---- atan-free direction classification ----
    float den0 = fmaf((float)gxx0, 0.015625f, EPSF);   // gxx/64 + eps, exact
    float den1 = fmaf((float)gxx1, 0.015625f, EPSF);
    float gy0 = (float)gyy0 * 0.015625f;
    float gy1 = (float)gyy1 * 0.015625f;
    float num0 = (gxyS0 > 0) ? -gy0 : gy0;             // s = sign(-gxy+eps)
    float num1 = (gxyS1 > 0) ? -gy1 : gy1;
    float an0 = fabsf(gy0), an1 = fabsf(gy1);
    float ad0 = fabsf(den0), ad1 = fabsf(den1);
    int rb0 = (int)(an0 >= T1C*ad0) + (int)(an0 >= T2C*ad0);
    int rb1 = (int)(an1 >= T1C*ad1) + (int)(an1 >= T2C*ad1);
    bool ng0 = ((__float_as_int(num0) ^ __float_as_int(den0)) < 0);
    bool ng1 = ((__float_as_int(num1) ^ __float_as_int(den1)) < 0);
    // r=+1->1, +2->2, 0->0, -1->0, -2->3
    int dir0 = ng0 ? ((rb0 == 2) ? 3 : 0) : rb0;
    int dir1 = ng1 ? ((rb1 == 2) ? 3 : 0) : rb1;

    // window rows: r0 = gh-2 .. r3 = gh+1 ; cols: [k .. k+4] = gw-2 .. gw+2
    const float* r0 = exr[(i+0)&3];
    const float* r1 = exr[(i+1)&3];
    const float* r2 = exr[(i+2)&3];
    const float* r3 = exr[(i+3)&3];

    float t12 = r2[1] + r2[2];
    float D0a = t12 + r2[0] + r2[3];                    // horizontal
    float D0b = t12 + r2[3] + r2[4];
    float D2a = (r0[2] + r1[2]) + (r2[2] + r3[2]);      // vertical
    float D2b = (r0[3] + r1[3]) + (r2[3] + r3[3]);
    float Dda = (r0[3] + r1[2]) + (r2[1] + r3[0]);      // anti-diagonal (dir 1&3)
    float Ddb = (r0[4] + r1[3]) + (r2[2] + r3[1]);

    float dena = (dir0 == 0) ? D0a : ((dir0 == 2) ? D2a : Dda);
    float denb = (dir1 == 0) ? D0b : ((dir1 == 2) ? D2b : Ddb);

    const int gh = h0 + hr0 + i;
    const bool hv = (gh >= 2) && (gh < Hn-2);
    float na = (hv && wvalid0) ? r2[2] : 0.f;
    float nb = (hv && wvalid1) ? r2[3] : 0.f;
    acc += na * fast_rcp(dena);
    acc += nb * fast_rcp(denb);
  }

  // ---- reduce: wave shuffle -> LDS -> one atomic per block into 256 slots ----
  #pragma unroll
  for (int off = 32; off > 0; off >>= 1)
    acc += __shfl_down(acc, off);
  if (lane == 0) wsum[wq] = acc;
  __syncthreads();
  if (tid == 0) {
    float s = 0.f;
    #pragma unroll
    for (int q = 0; q < NT/64; ++q) s += wsum[q];
    atomicAdd(&ws[(bz << 2) | (blockIdx.x & 3)], s);
  }
}

__global__ __launch_bounds__(64)
void reduce_ws_kernel(const float* __restrict__ ws, float* __restrict__ out)
{
  const int l = threadIdx.x;
  float s = (ws[l] + ws[l + 64]) + (ws[l + 128] + ws[l + 192]);
  #pragma unroll
  for (int off = 32; off > 0; off >>= 1)
    s += __shfl_down(s, off);
  if (l == 0) *out = s;
}

extern "C" void kernel_launch(void* const* d_in, const int* in_sizes, int n_in,
                              void* d_out, int out_size, void* d_ws, size_t ws_size,
                              hipStream_t stream) {
  (void)in_sizes; (void)n_in; (void)ws_size; (void)out_size;
  const float* pred   = (const float*)d_in[0];
  const int*   labels = (const int*)d_in[1];
  float* out = (float*)d_out;
  float* ws  = (float*)d_ws;

  // ws slots are re-poisoned (0xAA) before every timed launch -> zero them
  hipMemsetAsync(ws, 0, 256 * sizeof(float), stream);

  dim3 grid(Wn/TW, Hn/TH, Bn*Cn);   // 8 x 32 x 64 = 16384 blocks
  steal_nms_kernel<<<grid, NT, 0, stream>>>(pred, labels, ws);
  reduce_ws_kernel<<<1, 64, 0, stream>>>(ws, out);
}

// Round 4
// 263.547 us; speedup vs baseline: 1.1458x; 1.0072x over previous
//
#include <hip/hip_runtime.h>

// StealNMSLoss for MI355X (gfx950).  Round 4: two-phase split.
//
// Phase 1 (dir_kernel): per (b,pixel) compute 2-bit NMS direction for ALL 16
//   classes from the label map only; pack into u32/pixel dir-map in d_ws.
// Phase 2 (nms_sum_kernel): per (b,c,tile) stage exp(pred) tile, read dir-map,
//   pick 1-of-3 directional 4-sums, accumulate sum(exp/denom) over interior.
//
// Math notes (bit-exact vs reference, rounds 1-3):
//  - Composed Sobel-of-Sobel on a one-hot mask = exact integer stencils /64:
//      gxx = [1,4,6,4,1]_h (x) [1,0,-2,0,1]_w / 64
//      gxy = [-1,-2,0,2,1]_h (x) [-1,-2,0,2,1]_w / 64
//      gyy = [1,0,-2,0,1]_h (x) [1,4,6,4,1]_w / 64
//  - dir classification in exact integers: |gxx|,|gyy| <= 32; tan(pi/10) lies
//    between Farey neighbors 10/31 and 1/3 (det 1 -> no p/q, q<=32, strictly
//    between) so t1 = (100|gyy| > 33|gxx|); tan(3pi/10) between 11/8 and 40/29
//    -> t2 = (1000|gyy| > 1377|gxx|). gxx==0 (den=eps>0): t1/t2 reduce to
//    |gyy|>0, sign(den)=+  -- both match the float path. gyy==0 -> dir=0
//    regardless of ng. ng = (gyy<0) ^ (gxy>0) ^ (gxx<0).
//  - Only interior [2,H-2) x [2,W-2) contributes; dirs 1,3 share the
//    anti-diagonal denominator.
//
// Round 3 post-mortem: VALU-issue-bound (VALUBusy 60%), ~80% of it per-class
// label stencil work recomputed 16x/pixel -> moved to phase 1, done once.

#define Bn 4
#define Cn 16
#define Hn 512
#define Wn 1024

typedef unsigned long long u64;
typedef unsigned int u32;
typedef float f4u __attribute__((ext_vector_type(4), aligned(4)));
typedef int   i4u __attribute__((ext_vector_type(4), aligned(4)));

static __device__ __forceinline__ float fast_rcp(float x) {
#if __has_builtin(__builtin_amdgcn_rcpf)
  return __builtin_amdgcn_rcpf(x);
#else
  return 1.0f / x;
#endif
}

// ======================= Phase 1: direction map =======================
// Tile 128w x 8h, 256 threads = 32 tcols x 8 rows; thread owns 4 adjacent
// pixels in one row.  SWAR over 8 pixel-byte-lanes per u64.

#define P1TW 128
#define P1TH 8
#define P1LW 132
#define P1LH 12

__global__ __launch_bounds__(256)
void dir_kernel(const int* __restrict__ labels, u32* __restrict__ dirs)
{
  __shared__ unsigned char labt[P1LH][P1LW];

  const int w0 = blockIdx.x * P1TW;
  const int h0 = blockIdx.y * P1TH;
  const int b  = blockIdx.z;
  const int tid = threadIdx.x;

  const int* lbase = labels + (size_t)b * (Hn*Wn);
  const bool interior = (h0 >= 2) && (h0 + P1TH + 2 <= Hn) &&
                        (w0 >= 2) && (w0 + P1TW + 2 <= Wn);
  if (interior) {
    const int* lb = lbase + (size_t)(h0-2)*Wn + (w0-2);
    for (int i = tid; i < P1LH*33; i += 256) {
      int row = i / 33, c4 = (i - row*33) * 4;
      i4u L = *(const i4u*)(lb + row*Wn + c4);
      *(u32*)&labt[row][c4] =
          (u32)L.x | ((u32)L.y << 8) | ((u32)L.z << 16) | ((u32)L.w << 24);
    }
  } else {
    for (int i = tid; i < P1LH*33; i += 256) {
      int row = i / 33, c4 = (i - row*33) * 4;
      int gh = min(max(h0-2+row, 0), Hn-1);
      const int* lr = lbase + gh*Wn;
      u32 v = 0;
      #pragma unroll
      for (int k = 0; k < 4; ++k) {
        int gw = min(max(w0-2+c4+k, 0), Wn-1);
        v |= (u32)(lr[gw] & 0xff) << (8*k);
      }
      *(u32*)&labt[row][c4] = v;
    }
  }
  __syncthreads();

  const int tcol = tid & 31;
  const int trow = tid >> 5;

  // 5 window rows x 8 byte-cols (pixels at bytes 2..5 <-> gw = w0+4*tcol+0..3)
  u64 W[5];
  #pragma unroll
  for (int r = 0; r < 5; ++r) {
    const u32* lp = (const u32*)&labt[trow + r][0];
    u64 lo = lp[tcol];
    u64 hi = lp[tcol + 1];
    W[r] = lo | (hi << 32);
  }

  u32 pack[4] = {0u, 0u, 0u, 0u};

  #pragma unroll 1
  for (int c = 0; c < 16; ++c) {
    const u64 crep = 0x0101010101010101ULL * (u32)c;
    u64 m[5];
    #pragma unroll
    for (int r = 0; r < 5; ++r) {
      u64 x = W[r] ^ crep;
      m[r] = ((0x8080808080808080ULL - x) & 0x8080808080808080ULL) >> 7;
    }
    // vertical packed sums (pixel-byte lanes), all biases byte-safe:
    u64 t  = m[1] + m[3];
    u64 VA = m[0] + m[4] + (t << 2) + (m[2] << 2) + (m[2] << 1);          // [0,16]
    u64 VB = ((m[3] << 1) + m[4] + 0x0303030303030303ULL)
             - (m[0] + (m[1] << 1));                                       // [0,6]
    u64 VC = (m[0] + m[4] + 0x0202020202020202ULL) - (m[2] << 1);          // [0,4]
    // horizontal combine; result bytes k=0..3 = this thread's 4 pixels
    u64 gxxp = (VA + (VA >> 32) + 0x4040404040404040ULL) - ((VA >> 16) << 1);
    u64 q1   = (VC >> 8) + (VC >> 24);
    u64 w16  = VC >> 16;
    u64 gyyp = (VC + (VC >> 32)) + (q1 << 2) + (w16 << 2) + (w16 << 1);
    u64 gxyp = (((VB >> 24) << 1) + (VB >> 32) + 0x2020202020202020ULL)
             - (VB + ((VB >> 8) << 1));

    u32 gxxl = (u32)gxxp, gyyl = (u32)gyyp, gxyl = (u32)gxyp;
    #pragma unroll
    for (int k = 0; k < 4; ++k) {
      int gxx = (int)((gxxl >> (8*k)) & 0xffu) - 64;   // [-32,32]
      int gyy = (int)((gyyl >> (8*k)) & 0xffu) - 32;   // [-32,32]
      int gxyb = (int)((gxyl >> (8*k)) & 0xffu);       // >32 <=> gxy>0
      int ax = gxx < 0 ? -gxx : gxx;
      int ay = gyy < 0 ? -gyy : gyy;
      int t1 = (ay * 100  > ax * 33)   ? 1 : 0;
      int t2 = (ay * 1000 > ax * 1377) ? 1 : 0;
      int rb = t1 + t2;
      bool ng = ((gyy < 0) != (gxyb > 32)) != (gxx < 0);
      int dir = ng ? ((rb == 2) ? 3 : 0) : rb;
      pack[k] |= (u32)dir << (2*c);
    }
  }

  const int gh = h0 + trow;
  u32* drow = dirs + ((size_t)b*Hn + gh)*Wn + (w0 + 4*tcol);
  *(uint4*)drow = make_uint4(pack[0], pack[1], pack[2], pack[3]);
}

// ======================= Phase 2: exp / denom sum =======================

#define TW 128
#define TH 16
#define LW 132
#define LH 20
#define NT 256

__global__ __launch_bounds__(NT)
void nms_sum_kernel(const float* __restrict__ pred,
                    const u32* __restrict__ dirs,
                    float* __restrict__ slots)
{
  __shared__ float ext[LH][LW];
  __shared__ float wsum[NT/64];

  const int w0 = blockIdx.x * TW;
  const int h0 = blockIdx.y * TH;
  const int bz = blockIdx.z;
  const int b  = bz >> 4;
  const int c  = bz & 15;
  const int tid = threadIdx.x;

  const int lane = tid & 63;
  const int wq   = tid >> 6;
  const int hr0  = wq * 4;
  const int gw0  = w0 + 2*lane;

  // ---- prefetch this thread's 8 pixel dirs (u64 = 2 px, coalesced) ----
  u64 dp[4];
  {
    const u32* dbase = dirs + (size_t)b*Hn*Wn;
    #pragma unroll
    for (int i = 0; i < 4; ++i) {
      int gh = h0 + hr0 + i;
      dp[i] = *(const u64*)(dbase + (size_t)gh*Wn + gw0);
    }
  }

  // ---- stage exp tile ----
  const float* plane = pred + (size_t)(b*Cn + c) * (size_t)(Hn*Wn);
  const bool interior = (h0 >= 2) && (h0 + TH + 2 <= Hn) &&
                        (w0 >= 2) && (w0 + TW + 2 <= Wn);
  if (interior) {
    const float* pb = plane + (size_t)(h0-2)*Wn + (w0-2);
    for (int i = tid; i < LH*33; i += NT) {
      int row = i / 33, c4 = (i - row*33) * 4;
      f4u p = *(const f4u*)(pb + row*Wn + c4);
      float4 e;
      e.x = __expf(p.x); e.y = __expf(p.y); e.z = __expf(p.z); e.w = __expf(p.w);
      *(float4*)&ext[row][c4] = e;
    }
  } else {
    for (int i = tid; i < LH*(LW/2); i += NT) {
      int row = i / (LW/2);
      int col = (i - row*(LW/2)) * 2;
      int gh = min(max(h0-2+row, 0), Hn-1);
      int ga = min(max(w0-2+col,   0), Wn-1);
      int gb = min(max(w0-1+col,   0), Wn-1);
      const float* prow = plane + gh*Wn;
      *(float2*)&ext[row][col] = make_float2(__expf(prow[ga]), __expf(prow[gb]));
    }
  }
  __syncthreads();

  const bool wvalid0 = (gw0     >= 2) && (gw0     < Wn-2);
  const bool wvalid1 = (gw0 + 1 >= 2) && (gw0 + 1 < Wn-2);
  const u32 sh = 2u * (u32)c;   // uniform shift for dir extraction

  float acc = 0.f;

  // rolling 4-row exp register window
  float exr[4][5];
  const int fb = 2*lane;
  #pragma unroll
  for (int r = 0; r < 3; ++r) {
    float2 p0 = *(const float2*)&ext[hr0 + r][fb];
    float2 p1 = *(const float2*)&ext[hr0 + r][fb + 2];
    exr[r][0] = p0.x; exr[r][1] = p0.y;
    exr[r][2] = p1.x; exr[r][3] = p1.y;
    exr[r][4] = ext[hr0 + r][fb + 4];
  }

  #pragma unroll
  for (int i = 0; i < 4; ++i) {
    {
      const int rn = (i + 3) & 3;
      float2 p0 = *(const float2*)&ext[hr0 + i + 3][fb];
      float2 p1 = *(const float2*)&ext[hr0 + i + 3][fb + 2];
      exr[rn][0] = p0.x; exr[rn][1] = p0.y;
      exr[rn][2] = p1.x; exr[rn][3] = p1.y;
      exr[rn][4] = ext[hr0 + i + 3][fb + 4];
    }

    int dir0 = (int)(((u32)dp[i]        >> sh) & 3u);
    int dir1 = (int)(((u32)(dp[i] >> 32) >> sh) & 3u);

    const float* r0 = exr[(i+0)&3];
    const float* r1 = exr[(i+1)&3];
    const float* r2 = exr[(i+2)&3];
    const float* r3 = exr[(i+3)&3];

    float t12 = r2[1] + r2[2];
    float D0a = t12 + r2[0] + r2[3];                    // horizontal
    float D0b = t12 + r2[3] + r2[4];
    float D2a = (r0[2] + r1[2]) + (r2[2] + r3[2]);      // vertical
    float D2b = (r0[3] + r1[3]) + (r2[3] + r3[3]);
    float Dda = (r0[3] + r1[2]) + (r2[1] + r3[0]);      // anti-diagonal (1&3)
    float Ddb = (r0[4] + r1[3]) + (r2[2] + r3[1]);

    float dena = (dir0 == 0) ? D0a : ((dir0 == 2) ? D2a : Dda);
    float denb = (dir1 == 0) ? D0b : ((dir1 == 2) ? D2b : Ddb);

    const int gh = h0 + hr0 + i;
    const bool hv = (gh >= 2) && (gh < Hn-2);
    float na = (hv && wvalid0) ? r2[2] : 0.f;
    float nb = (hv && wvalid1) ? r2[3] : 0.f;
    acc += na * fast_rcp(dena);
    acc += nb * fast_rcp(denb);
  }

  #pragma unroll
  for (int off = 32; off > 0; off >>= 1)
    acc += __shfl_down(acc, off);
  if (lane == 0) wsum[wq] = acc;
  __syncthreads();
  if (tid == 0) {
    float s = 0.f;
    #pragma unroll
    for (int q = 0; q < NT/64; ++q) s += wsum[q];
    atomicAdd(&slots[(bz << 2) | (blockIdx.x & 3)], s);
  }
}

__global__ __launch_bounds__(64)
void reduce_ws_kernel(const float* __restrict__ slots, float* __restrict__ out)
{
  const int l = threadIdx.x;
  float s = (slots[l] + slots[l + 64]) + (slots[l + 128] + slots[l + 192]);
  #pragma unroll
  for (int off = 32; off > 0; off >>= 1)
    s += __shfl_down(s, off);
  if (l == 0) *out = s;
}

extern "C" void kernel_launch(void* const* d_in, const int* in_sizes, int n_in,
                              void* d_out, int out_size, void* d_ws, size_t ws_size,
                              hipStream_t stream) {
  (void)in_sizes; (void)n_in; (void)ws_size; (void)out_size;
  const float* pred   = (const float*)d_in[0];
  const int*   labels = (const int*)d_in[1];
  float* out = (float*)d_out;

  // d_ws layout: [0, 8 MB) u32 dir-map (fully overwritten by phase 1 each
  // call), then 256 float reduction slots.  Needs ws_size >= 8389632 B.
  u32*   dirs  = (u32*)d_ws;
  float* slots = (float*)((char*)d_ws + (size_t)Bn*Hn*Wn*sizeof(u32));

  hipMemsetAsync(slots, 0, 256 * sizeof(float), stream);

  dir_kernel<<<dim3(Wn/P1TW, Hn/P1TH, Bn), 256, 0, stream>>>(labels, dirs);
  nms_sum_kernel<<<dim3(Wn/TW, Hn/TH, Bn*Cn), NT, 0, stream>>>(pred, dirs, slots);
  reduce_ws_kernel<<<1, 64, 0, stream>>>(slots, out);
}

// Round 5
// 247.309 us; speedup vs baseline: 1.2210x; 1.0657x over previous
//
#include <hip/hip_runtime.h>

// StealNMSLoss for MI355X (gfx950).  Round 5: dir-indexed LDS gather.
//
// Phase 1 (dir_kernel): per (b,pixel) compute 2-bit NMS direction for ALL 16
//   classes from the label map only; pack into u32/pixel dir-map in d_ws.
// Phase 2 (nms_sum_kernel): per (b,c,tile) stage exp(pred) tile in LDS; per
//   pixel, build 4 LDS addresses from its 2-bit dir and gather the ONE needed
//   denominator (4 reads + 3 adds), numerator = own exp (5th read).  All
//   gather offsets are within the 2-px halo -> always in-bounds, no clamps.
//
// Math notes (bit-exact vs reference, rounds 1-4):
//  - Composed Sobel-of-Sobel on one-hot mask = exact integer stencils /64:
//      gxx = [1,4,6,4,1]_h (x) [1,0,-2,0,1]_w / 64
//      gxy = [-1,-2,0,2,1]_h (x) [-1,-2,0,2,1]_w / 64
//      gyy = [1,0,-2,0,1]_h (x) [1,4,6,4,1]_w / 64
//  - dir classification in exact integers (|gxx|,|gyy| <= 32): tan(pi/10)
//    lies between Farey neighbors 10/31, 1/3 -> t1 = (100|gyy| > 33|gxx|);
//    tan(3pi/10) between 11/8, 40/29 -> t2 = (1000|gyy| > 1377|gxx|).
//    gxx==0 (den=eps>0) and gyy==0 cases verified to match the float path.
//    ng = (gyy<0) ^ (gxy>0) ^ (gxx<0).
//  - Only interior [2,H-2) x [2,W-2) contributes; dirs 1,3 share the
//    anti-diagonal denominator (same offset set).
//  - Gather element offsets (row stride LW=132):
//      dir0 (horiz): {-2,-1,0,+1}
//      dir2 (vert):  {-264,-132,0,+132}
//      dir1/3 (anti-diag): {-263,-132,-1,+130}
//    ascending order == reference's j=-2..1 add order for dirs 0,1,2.
//
// Round 4 post-mortem: nms_sum 90us, VALU 37%: ~40 VALU inst/px from rolling
// window + 3-sweep denominators.  Gather form: ~20 VALU + 5 LDS reads/px.

#define Bn 4
#define Cn 16
#define Hn 512
#define Wn 1024

typedef unsigned long long u64;
typedef unsigned int u32;
typedef float f4u __attribute__((ext_vector_type(4), aligned(4)));
typedef int   i4u __attribute__((ext_vector_type(4), aligned(4)));

static __device__ __forceinline__ float fast_rcp(float x) {
#if __has_builtin(__builtin_amdgcn_rcpf)
  return __builtin_amdgcn_rcpf(x);
#else
  return 1.0f / x;
#endif
}

// ======================= Phase 1: direction map =======================
// Tile 128w x 8h, 256 threads = 32 tcols x 8 rows; thread owns 4 adjacent
// pixels in one row.  SWAR over 8 pixel-byte-lanes per u64.

#define P1TW 128
#define P1TH 8
#define P1LW 132
#define P1LH 12

__global__ __launch_bounds__(256)
void dir_kernel(const int* __restrict__ labels, u32* __restrict__ dirs)
{
  __shared__ unsigned char labt[P1LH][P1LW];

  const int w0 = blockIdx.x * P1TW;
  const int h0 = blockIdx.y * P1TH;
  const int b  = blockIdx.z;
  const int tid = threadIdx.x;

  const int* lbase = labels + (size_t)b * (Hn*Wn);
  const bool interior = (h0 >= 2) && (h0 + P1TH + 2 <= Hn) &&
                        (w0 >= 2) && (w0 + P1TW + 2 <= Wn);
  if (interior) {
    const int* lb = lbase + (size_t)(h0-2)*Wn + (w0-2);
    for (int i = tid; i < P1LH*33; i += 256) {
      int row = i / 33, c4 = (i - row*33) * 4;
      i4u L = *(const i4u*)(lb + row*Wn + c4);
      *(u32*)&labt[row][c4] =
          (u32)L.x | ((u32)L.y << 8) | ((u32)L.z << 16) | ((u32)L.w << 24);
    }
  } else {
    for (int i = tid; i < P1LH*33; i += 256) {
      int row = i / 33, c4 = (i - row*33) * 4;
      int gh = min(max(h0-2+row, 0), Hn-1);
      const int* lr = lbase + gh*Wn;
      u32 v = 0;
      #pragma unroll
      for (int k = 0; k < 4; ++k) {
        int gw = min(max(w0-2+c4+k, 0), Wn-1);
        v |= (u32)(lr[gw] & 0xff) << (8*k);
      }
      *(u32*)&labt[row][c4] = v;
    }
  }
  __syncthreads();

  const int tcol = tid & 31;
  const int trow = tid >> 5;

  // 5 window rows x 8 byte-cols (pixels at bytes 2..5 <-> gw = w0+4*tcol+0..3)
  u64 W[5];
  #pragma unroll
  for (int r = 0; r < 5; ++r) {
    const u32* lp = (const u32*)&labt[trow + r][0];
    u64 lo = lp[tcol];
    u64 hi = lp[tcol + 1];
    W[r] = lo | (hi << 32);
  }

  u32 pack[4] = {0u, 0u, 0u, 0u};

  #pragma unroll 1
  for (int c = 0; c < 16; ++c) {
    const u64 crep = 0x0101010101010101ULL * (u32)c;
    u64 m[5];
    #pragma unroll
    for (int r = 0; r < 5; ++r) {
      u64 x = W[r] ^ crep;
      m[r] = ((0x8080808080808080ULL - x) & 0x8080808080808080ULL) >> 7;
    }
    // vertical packed sums (pixel-byte lanes), all biases byte-safe:
    u64 t  = m[1] + m[3];
    u64 VA = m[0] + m[4] + (t << 2) + (m[2] << 2) + (m[2] << 1);          // [0,16]
    u64 VB = ((m[3] << 1) + m[4] + 0x0303030303030303ULL)
             - (m[0] + (m[1] << 1));                                       // [0,6]
    u64 VC = (m[0] + m[4] + 0x0202020202020202ULL) - (m[2] << 1);          // [0,4]
    // horizontal combine; result bytes k=0..3 = this thread's 4 pixels
    u64 gxxp = (VA + (VA >> 32) + 0x4040404040404040ULL) - ((VA >> 16) << 1);
    u64 q1   = (VC >> 8) + (VC >> 24);
    u64 w16  = VC >> 16;
    u64 gyyp = (VC + (VC >> 32)) + (q1 << 2) + (w16 << 2) + (w16 << 1);
    u64 gxyp = (((VB >> 24) << 1) + (VB >> 32) + 0x2020202020202020ULL)
             - (VB + ((VB >> 8) << 1));

    u32 gxxl = (u32)gxxp, gyyl = (u32)gyyp, gxyl = (u32)gxyp;
    #pragma unroll
    for (int k = 0; k < 4; ++k) {
      int gxx = (int)((gxxl >> (8*k)) & 0xffu) - 64;   // [-32,32]
      int gyy = (int)((gyyl >> (8*k)) & 0xffu) - 32;   // [-32,32]
      int gxyb = (int)((gxyl >> (8*k)) & 0xffu);       // >32 <=> gxy>0
      int ax = gxx < 0 ? -gxx : gxx;
      int ay = gyy < 0 ? -gyy : gyy;
      // __mul24: full-rate v_mul_u32_u24 (v_mul_lo_u32 is quarter-rate)
      int t1 = (__mul24(ay, 100)  > __mul24(ax, 33))   ? 1 : 0;
      int t2 = (__mul24(ay, 1000) > __mul24(ax, 1377)) ? 1 : 0;
      int rb = t1 + t2;
      bool ng = ((gyy < 0) != (gxyb > 32)) != (gxx < 0);
      int dir = ng ? ((rb == 2) ? 3 : 0) : rb;
      pack[k] |= (u32)dir << (2*c);
    }
  }

  const int gh = h0 + trow;
  u32* drow = dirs + ((size_t)b*Hn + gh)*Wn + (w0 + 4*tcol);
  *(uint4*)drow = make_uint4(pack[0], pack[1], pack[2], pack[3]);
}

// ======================= Phase 2: exp / denom sum =======================

#define TW 128
#define TH 32
#define LW 132
#define LH 36
#define NT 256

__global__ __launch_bounds__(NT)
void nms_sum_kernel(const float* __restrict__ pred,
                    const u32* __restrict__ dirs,
                    float* __restrict__ slots)
{
  __shared__ float ext[LH*LW];
  __shared__ float wsum[NT/64];

  const int w0 = blockIdx.x * TW;
  const int h0 = blockIdx.y * TH;
  const int bz = blockIdx.z;
  const int b  = bz >> 4;
  const int c  = bz & 15;
  const int tid = threadIdx.x;

  // compute-phase mapping: 256 threads = 2 row-groups x 128 cols
  const int x  = tid & 127;       // tile col
  const int rg = tid >> 7;        // row group: rows rg*16 .. rg*16+15
  const int gw = w0 + x;

  // ---- prefetch this thread's 16 dir words (issued before the barrier;
  //      dirs plane is 8 MB, reused by 16 class-blocks -> L2/L3 hits) ----
  const u32* dbase = dirs + (size_t)b*Hn*Wn + (size_t)(h0 + rg*16)*Wn + gw;
  u32 dv[16];
  #pragma unroll
  for (int r = 0; r < 16; ++r) dv[r] = dbase[(size_t)r*Wn];

  // ---- stage exp tile ----
  const float* plane = pred + (size_t)(b*Cn + c) * (size_t)(Hn*Wn);
  const bool interior = (h0 >= 2) && (h0 + TH + 2 <= Hn) &&
                        (w0 >= 2) && (w0 + TW + 2 <= Wn);
  if (interior) {
    const float* pb = plane + (size_t)(h0-2)*Wn + (w0-2);
    for (int i = tid; i < LH*33; i += NT) {
      int row = i / 33, c4 = (i - row*33) * 4;
      f4u p = *(const f4u*)(pb + row*Wn + c4);
      float4 e;
      e.x = __expf(p.x); e.y = __expf(p.y); e.z = __expf(p.z); e.w = __expf(p.w);
      *(float4*)&ext[row*LW + c4] = e;
    }
  } else {
    for (int i = tid; i < LH*(LW/2); i += NT) {
      int row = i / (LW/2);
      int col = (i - row*(LW/2)) * 2;
      int gh = min(max(h0-2+row, 0), Hn-1);
      int ga = min(max(w0-2+col,   0), Wn-1);
      int gb = min(max(w0-1+col,   0), Wn-1);
      const float* prow = plane + gh*Wn;
      *(float2*)&ext[row*LW+col] = make_float2(__expf(prow[ga]), __expf(prow[gb]));
    }
  }
  __syncthreads();

  const bool wv = (gw >= 2) && (gw < Wn-2);
  const u32 sh = 2u * (u32)c;
  const int ghb = h0 + rg*16;

  float acc = 0.f;
  const int abase = (rg*16 + 2)*LW + (x + 2);   // LDS element index of pixel row r=0

  #pragma unroll
  for (int r = 0; r < 16; ++r) {
    const int a0 = abase + r*LW;
    const int dir = (int)((dv[r] >> sh) & 3u);

    // dir-dependent gather offsets (elements); always within staged halo.
    const int o0 = (dir == 0) ? -2 : ((dir == 2) ? -264 : -263);
    const int o1 = (dir == 0) ? -1 : -132;
    const int o2 = -(dir & 1);
    const int o3 = (dir == 0) ?  1 : ((dir == 2) ?  132 :  130);

    float g0 = ext[a0 + o0];
    float g1 = ext[a0 + o1];
    float g2 = ext[a0 + o2];
    float g3 = ext[a0 + o3];
    float num = ext[a0];
    float den = ((g0 + g1) + g2) + g3;

    const int gh = ghb + r;
    const bool hv = (gh >= 2) && (gh < Hn-2);
    float nn = (hv && wv) ? num : 0.f;
    acc += nn * fast_rcp(den);
  }

  // ---- reduce: wave shuffle -> LDS -> one atomic per block into 256 slots ----
  const int lane = tid & 63;
  const int wq   = tid >> 6;
  #pragma unroll
  for (int off = 32; off > 0; off >>= 1)
    acc += __shfl_down(acc, off);
  if (lane == 0) wsum[wq] = acc;
  __syncthreads();
  if (tid == 0) {
    float s = 0.f;
    #pragma unroll
    for (int q = 0; q < NT/64; ++q) s += wsum[q];
    atomicAdd(&slots[(bz << 2) | (blockIdx.x & 3)], s);
  }
}

__global__ __launch_bounds__(64)
void reduce_ws_kernel(const float* __restrict__ slots, float* __restrict__ out)
{
  const int l = threadIdx.x;
  float s = (slots[l] + slots[l + 64]) + (slots[l + 128] + slots[l + 192]);
  #pragma unroll
  for (int off = 32; off > 0; off >>= 1)
    s += __shfl_down(s, off);
  if (l == 0) *out = s;
}

extern "C" void kernel_launch(void* const* d_in, const int* in_sizes, int n_in,
                              void* d_out, int out_size, void* d_ws, size_t ws_size,
                              hipStream_t stream) {
  (void)in_sizes; (void)n_in; (void)ws_size; (void)out_size;
  const float* pred   = (const float*)d_in[0];
  const int*   labels = (const int*)d_in[1];
  float* out = (float*)d_out;

  // d_ws layout: [0, 8 MB) u32 dir-map (fully overwritten by phase 1 each
  // call), then 256 float reduction slots.  Needs ws_size >= 8389632 B.
  u32*   dirs  = (u32*)d_ws;
  float* slots = (float*)((char*)d_ws + (size_t)Bn*Hn*Wn*sizeof(u32));

  hipMemsetAsync(slots, 0, 256 * sizeof(float), stream);

  dir_kernel<<<dim3(Wn/P1TW, Hn/P1TH, Bn), 256, 0, stream>>>(labels, dirs);
  nms_sum_kernel<<<dim3(Wn/TW, Hn/TH, Bn*Cn), NT, 0, stream>>>(pred, dirs, slots);
  reduce_ws_kernel<<<1, 64, 0, stream>>>(slots, out);
}